// Round 10
// baseline (203.488 us; speedup 1.0000x reference)
//
#include <hip/hip_runtime.h>

typedef __bf16 bf16;
typedef __bf16 bf16x8 __attribute__((ext_vector_type(8)));
typedef __bf16 bf16x4 __attribute__((ext_vector_type(4)));
typedef float  f32x4  __attribute__((ext_vector_type(4)));

#define MFMA_BF16(a, b, c) __builtin_amdgcn_mfma_f32_16x16x32_bf16((a), (b), (c), 0, 0, 0)

// Problem constants: B=2, L=2048, E=1024, H=16, D=64; M=B*L=4096, K=N=E=1024.

__device__ __forceinline__ void async_load16(const bf16* g, const bf16* l) {
    auto gp = (const __attribute__((address_space(1))) unsigned int*)(unsigned long long)(const void*)g;
    auto lp = (__attribute__((address_space(3))) unsigned int*)(unsigned int)(unsigned long long)(const void*)l;
    __builtin_amdgcn_global_load_lds(gp, lp, 16, 0, 0);
}

// ---------------------------------------------------------------------------
// fp32 -> bf16 conversion. Flat 1D grid (16384 blocks), 4 elems/thread.
// Layout: 3 activations of 2^22 elems, then 4 weights of 2^20 elems.
__global__ void cvt_bf16_kernel(
    const float* __restrict__ s0, const float* __restrict__ s1, const float* __restrict__ s2,
    const float* __restrict__ s3, const float* __restrict__ s4, const float* __restrict__ s5,
    const float* __restrict__ s6,
    bf16* __restrict__ d0, bf16* __restrict__ d1, bf16* __restrict__ d2,
    bf16* __restrict__ d3, bf16* __restrict__ d4, bf16* __restrict__ d5,
    bf16* __restrict__ d6)
{
    unsigned e = (blockIdx.x * 256 + threadIdx.x) * 4;
    const float* src; bf16* dst; unsigned off;
    if (e < 12582912u) {
        unsigned which = e >> 22;
        src = which == 0 ? s0 : (which == 1 ? s1 : s2);
        dst = which == 0 ? d0 : (which == 1 ? d1 : d2);
        off = e & 4194303u;
    } else {
        unsigned ew = e - 12582912u;
        unsigned which = ew >> 20;
        src = which == 0 ? s3 : (which == 1 ? s4 : (which == 2 ? s5 : s6));
        dst = which == 0 ? d3 : (which == 1 ? d4 : (which == 2 ? d5 : d6));
        off = ew & 1048575u;
    }
    float4 f = *(const float4*)(src + off);
    bf16x4 o;
    o.x = (bf16)f.x; o.y = (bf16)f.y; o.z = (bf16)f.z; o.w = (bf16)f.w;
    *(bf16x4*)(dst + off) = o;
}

// ---------------------------------------------------------------------------
// Tiled bf16 GEMM, BM=128 x BN (template), BK=32 x 2 stripes/barrier,
// 4 waves (2x2).
//
// XCD-aware tile remap (T1): HW assigns xcd = blockid % 8, and blockid =
// blockIdx.x + 8*blockIdx.y, so without remap each XCD got ONE feature-tile
// x ALL token-tiles -> zero B-panel reuse inside an XCD L2 (measured 101 MB
// FETCH vs ~30 MB ideal). Remap: c = flat&7 (the XCD), j = flat>>3;
// feature_tile = j&7, token_tile = c*(gy/8) + (j>>3). Per-XCD working set =
// weights 2 MB + token-panels 1 MB < 4 MB L2.  [R3: gemm4<128> left top-5]
//
// Two BK=32 stripes staged per barrier pair: halves lockstep drains (32->16).
//
// R9: output projection (z=3) moved from BN=64/512-block to this same
// BN=128/256-block shape -- 1.5x less staging bytes/FLOP, 2x fewer
// barrier-drains/FLOP than the 128x64 tile it used before.
//
// Orientation per output so the 4 r-values (C/D rows) are address-consecutive
// in the destination -> all stores bf16x4/float4:
//  z=0 (A=Wq, B=Xq): +bq, *0.125*log2e -> Qs [B,H,L,D]
//  z=1 (A=Wk, B=Xk): -> Ksw fragment-major (d lands on j)
//  z=2 (A=Xv, B=Wv): -> Vsw fragment-major (token lands on j)
//  z=3 (A=Wo, B=attn): +bo -> out fp32 (feature-contiguous float4)
template<int BN>
__global__ __launch_bounds__(256, (BN == 128) ? 2 : 4) void gemm4_kernel(
    const bf16* __restrict__ Xq, const bf16* __restrict__ Xk, const bf16* __restrict__ Xv,
    const bf16* __restrict__ Ao,
    const bf16* __restrict__ Wq, const bf16* __restrict__ Wk, const bf16* __restrict__ Wv,
    const bf16* __restrict__ Wo,
    const float* __restrict__ bq, const float* __restrict__ bo,
    bf16* __restrict__ Qs, bf16* __restrict__ Ksw, bf16* __restrict__ Vsw,
    float* __restrict__ out, int zbase)
{
    const int z = zbase + blockIdx.z;
    const bf16 *Amat, *Bmat;
    if (z == 0)      { Amat = Wq; Bmat = Xq; }
    else if (z == 1) { Amat = Wk; Bmat = Xk; }
    else if (z == 2) { Amat = Xv; Bmat = Wv; }
    else             { Amat = Wo; Bmat = Ao; }

    // XCD-aware remap (bijective: gy is a multiple of 8 for both launches)
    const int flat = blockIdx.x + 8 * blockIdx.y;
    const int c    = flat & 7;           // XCD (blockid % 8)
    const int j    = flat >> 3;          // position within this XCD's chunk
    const int ft   = j & 7;              // feature tile (8 x 128)
    const int tt   = c * (gridDim.y >> 3) + (j >> 3);  // token tile

    const int m0 = (z == 2 ? tt : ft) * 128;
    const int n0 = (z == 2 ? ft : tt) * BN;

    __shared__ __align__(16) bf16 lA[2][128 * 32];
    __shared__ __align__(16) bf16 lB[2][BN * 32];

    const int tid  = threadIdx.x;
    const int w    = tid >> 6;
    const int lane = tid & 63;
    const int lm   = lane & 15;
    const int g    = lane >> 4;
    const int wm   = (w & 1) * 64;
    const int wn   = (w >> 1) * (BN / 2);
    constexpr int NT = BN / 32;
    constexpr int T  = (128 + BN) / 64;

    f32x4 acc[4][NT] = {};

    for (int kb2 = 0; kb2 < 16; kb2++) {
        __syncthreads();
#pragma unroll
        for (int st = 0; st < 2; st++) {
            int kb = kb2 * 2 + st;
#pragma unroll
            for (int t = 0; t < T; t++) {
                int s   = (t * 4 + w) * 64 + lane;
                int row = s >> 2;
                int gs  = s & 3;
                int gg  = gs ^ ((row >> 1) & 3);
                if (row < 128)
                    async_load16(Amat + (size_t)(m0 + row) * 1024 + kb * 32 + gg * 8,
                                 lA[st] + s * 8);
                else
                    async_load16(Bmat + (size_t)(n0 + row - 128) * 1024 + kb * 32 + gg * 8,
                                 lB[st] + (s - 512) * 8);
            }
        }
        __syncthreads();

#pragma unroll
        for (int st = 0; st < 2; st++) {
            bf16x8 af[4], bfr[NT];
#pragma unroll
            for (int mt = 0; mt < 4; mt++) {
                int row = wm + mt * 16 + lm;
                af[mt] = *(const bf16x8*)(lA[st] + row * 32 + ((g ^ ((row >> 1) & 3)) << 3));
            }
#pragma unroll
            for (int nt = 0; nt < NT; nt++) {
                int row = wn + nt * 16 + lm;
                bfr[nt] = *(const bf16x8*)(lB[st] + row * 32 + ((g ^ ((row >> 1) & 3)) << 3));
            }
#pragma unroll
            for (int mt = 0; mt < 4; mt++)
#pragma unroll
                for (int nt = 0; nt < NT; nt++)
                    acc[mt][nt] = MFMA_BF16(af[mt], bfr[nt], acc[mt][nt]);
        }
    }

    if (z == 3) {
#pragma unroll
        for (int mt = 0; mt < 4; mt++) {
            int mb = m0 + wm + mt * 16 + g * 4;
            f32x4 bov = *(const f32x4*)(bo + mb);
#pragma unroll
            for (int nt = 0; nt < NT; nt++) {
                int n = n0 + wn + nt * 16 + lm;
                f32x4 val;
#pragma unroll
                for (int r = 0; r < 4; r++) val[r] = acc[mt][nt][r] + bov[r];
                *(f32x4*)(out + (size_t)n * 1024 + mb) = val;
            }
        }
    } else if (z == 2) {
#pragma unroll
        for (int mt = 0; mt < 4; mt++) {
            int mb   = m0 + wm + mt * 16 + g * 4;
            int b    = mb >> 11;
            int lpos = mb & 2047;
            int kb2  = lpos >> 6, kc = (lpos >> 5) & 1, gv = (lpos >> 3) & 3, j0 = lpos & 7;
#pragma unroll
            for (int nt = 0; nt < NT; nt++) {
                int n = n0 + wn + nt * 16 + lm;
                int h = n >> 6, mt2 = (n >> 4) & 3, lmv = n & 15;
                bf16x4 ov;
#pragma unroll
                for (int r = 0; r < 4; r++) ov[r] = (bf16)acc[mt][nt][r];
                *(bf16x4*)(Vsw + (size_t)(b * 16 + h) * 131072 +
                           (size_t)((kb2 * 8 + mt2 * 2 + kc) * 64 + gv * 16 + lmv) * 8 + j0) = ov;
            }
        }
    } else if (z == 1) {
#pragma unroll
        for (int mt = 0; mt < 4; mt++) {
            int mb = m0 + wm + mt * 16 + g * 4;
            int h  = mb >> 6;
            int f  = (mb >> 5) & 1, gk = (mb >> 3) & 3, j0 = mb & 7;
#pragma unroll
            for (int nt = 0; nt < NT; nt++) {
                int n    = n0 + wn + nt * 16 + lm;
                int b    = n >> 11;
                int lpos = n & 2047;
                int kb2  = lpos >> 6;
                int rem  = lpos & 63;
                int cc   = ((rem >> 4) & 2) | ((rem >> 2) & 1);
                int lmk  = ((rem >> 1) & 12) | (rem & 3);
                bf16x4 ov;
#pragma unroll
                for (int r = 0; r < 4; r++) ov[r] = (bf16)acc[mt][nt][r];
                *(bf16x4*)(Ksw + (size_t)(b * 16 + h) * 131072 +
                           (size_t)((kb2 * 8 + cc * 2 + f) * 64 + gk * 16 + lmk) * 8 + j0) = ov;
            }
        }
    } else {
        const float qscale = 0.18033688011112042f;  // 1/8 * log2(e)
#pragma unroll
        for (int mt = 0; mt < 4; mt++) {
            int mb  = m0 + wm + mt * 16 + g * 4;
            int h   = mb >> 6;
            int dd0 = mb & 63;
            f32x4 bqv = *(const f32x4*)(bq + mb);
#pragma unroll
            for (int nt = 0; nt < NT; nt++) {
                int n    = n0 + wn + nt * 16 + lm;
                int b    = n >> 11;
                int lpos = n & 2047;
                bf16x4 ov;
#pragma unroll
                for (int r = 0; r < 4; r++)
                    ov[r] = (bf16)((acc[mt][nt][r] + bqv[r]) * qscale);
                *(bf16x4*)(Qs + (size_t)((b * 16 + h) * 2048 + lpos) * 64 + dd0) = ov;
            }
        }
    }
}

// ---------------------------------------------------------------------------
// Flash attention v10 (BEST: 196.6 us total): K-split, 8 waves,
// register-direct, MFMA denominator. R9's s_sleep stagger regressed +1.7 us
// (phase offset does not persist across iterations -- pair re-locks at the
// first memory stall), reverted.
// Structure: 256 blocks x 8 waves (2/SIMD); wave w: q-chunk (w&3)*64,
// k-half (w>>2)*1024 tokens. The no-max softmax (p = exp2(s)) makes
// disjoint-k partial (O, lsum) exactly additive -> one LDS combine pass.
// Denominator rides the matrix pipe: ones-row MFMA column-sums P (replaces
// ~64 VALU adds/iter + end shuffles; every lane ends with the full sum).
__global__ __launch_bounds__(512, 2) void attn_kernel(
    const bf16* __restrict__ Qs, const bf16* __restrict__ Ksw,
    const bf16* __restrict__ Vsw, bf16* __restrict__ attn)
{
    const int tid  = threadIdx.x;
    const int w    = tid >> 6;        // 0..7
    const int wq   = w & 3;           // q sub-chunk
    const int wk   = w >> 2;          // k half
    const int lane = tid & 63;
    const int lm   = lane & 15;
    const int g    = lane >> 4;
    const int i    = blockIdx.x;      // 256 blocks
    const int bh   = ((i & 7) << 2) | ((i >> 3) & 3);  // 4 heads per XCD
    const int q0   = (i >> 5) * 256 + wq * 64;         // 64 q-rows per wave

    const bf16* Qh = Qs  + (size_t)bh * 131072;
    const bf16* Kh = Ksw + (size_t)bh * 131072 + (size_t)wk * 65536;  // k-half base
    const bf16* Vh = Vsw + (size_t)bh * 131072 + (size_t)wk * 65536;

    // psum: 4 x 64 x 68 f32 (cols 0..63 = partial O, col 64 = partial lsum)
    // ost: 4 waves x 64 x 72 bf16. Total ~104 KB -> 1 block/CU.
    __shared__ __align__(16) float psum[4][64][68];
    __shared__ __align__(16) bf16 ost[4][64 * 72];

    // Q fragments (B operand): lane lm = q-row, k(=d) = f*32 + g*8 + j
    bf16x8 qf[4][2];
#pragma unroll
    for (int qi = 0; qi < 4; qi++)
#pragma unroll
        for (int f = 0; f < 2; f++)
            qf[qi][f] = *(const bf16x8*)(Qh + (size_t)(q0 + qi * 16 + lm) * 64 + f * 32 + g * 8);

    const f32x4 fzero = {0.0f, 0.0f, 0.0f, 0.0f};
    f32x4 o[4][4] = {};
    f32x4 ol[4] = {};                 // denominator accumulators (ones-row MFMA)
    const bf16x8 ones = {(bf16)1.0f, (bf16)1.0f, (bf16)1.0f, (bf16)1.0f,
                         (bf16)1.0f, (bf16)1.0f, (bf16)1.0f, (bf16)1.0f};

    // prologue: stripe-0 (of this k-half) fragments into registers
    bf16x8 kf[8], vf[8];
#pragma unroll
    for (int t = 0; t < 8; t++)
        kf[t] = *(const bf16x8*)(Kh + ((size_t)t * 64 + lane) * 8);
#pragma unroll
    for (int t = 0; t < 8; t++)
        vf[t] = *(const bf16x8*)(Vh + ((size_t)t * 64 + lane) * 8);

    for (int kb = 0; kb < 16; kb++) {
        // next-stripe base (clamped: last iteration re-reads stripe 15, unused)
        const int kn = (kb < 15) ? kb + 1 : 15;
        const bf16* Kn = Kh + (size_t)kn * 4096;
        const bf16* Vn = Vh + (size_t)kn * 4096;

        // QK^T + softmax per fragment (4 independent chains -> ILP):
        // s[c][r] = S at k = 32*(c>>1) + 8g + 4*(c&1) + r, q = lm
        bf16x8 pb[4][2];
        __builtin_amdgcn_s_setprio(1);
#pragma unroll
        for (int qi = 0; qi < 4; qi++) {
            f32x4 s[4];
#pragma unroll
            for (int c = 0; c < 4; c++) {
                s[c] = MFMA_BF16(kf[2 * c],     qf[qi][0], fzero);
                s[c] = MFMA_BF16(kf[2 * c + 1], qf[qi][1], s[c]);
            }
            // flat p[]: index kc*8 + j, j 0..3 <- s[2kc][j], j 4..7 <- s[2kc+1][j-4]
            float p[16];
#pragma unroll
            for (int c = 0; c < 4; c++)
#pragma unroll
                for (int r = 0; r < 4; r++)
                    p[(c >> 1) * 8 + (c & 1) * 4 + r] = __builtin_amdgcn_exp2f(s[c][r]);
#pragma unroll
            for (int kc = 0; kc < 2; kc++)
#pragma unroll
                for (int jj = 0; jj < 8; jj++)     // adjacent writes -> cvt_pk
                    pb[qi][kc][jj] = (bf16)p[kc * 8 + jj];
        }
        __builtin_amdgcn_s_setprio(0);

        // reload kf with next stripe -- latency hides under PV (40 MFMAs)
#pragma unroll
        for (int t = 0; t < 8; t++)
            kf[t] = *(const bf16x8*)(Kn + ((size_t)t * 64 + lane) * 8);

        // O^T += V^T P (shared vf fragment feeds all 4 q-fragments);
        // denominator rides the matrix pipe: ones-row MFMA sums P columns.
        __builtin_amdgcn_s_setprio(1);
#pragma unroll
        for (int kc = 0; kc < 2; kc++) {
#pragma unroll
            for (int mt = 0; mt < 4; mt++) {
                bf16x8 vfv = vf[mt * 2 + kc];
#pragma unroll
                for (int qi = 0; qi < 4; qi++)
                    o[qi][mt] = MFMA_BF16(vfv, pb[qi][kc], o[qi][mt]);
            }
#pragma unroll
            for (int qi = 0; qi < 4; qi++)
                ol[qi] = MFMA_BF16(ones, pb[qi][kc], ol[qi]);
        }
        __builtin_amdgcn_s_setprio(0);

        // reload vf with next stripe -- hides under next QK^T + softmax
#pragma unroll
        for (int t = 0; t < 8; t++)
            vf[t] = *(const bf16x8*)(Vn + ((size_t)t * 64 + lane) * 8);
    }

    // ol[qi][r] now holds sum_k P[q=qi*16+lm, k] over this k-half,
    // replicated across r and across g -- no shuffles needed.

    // k-split combine: waves 4-7 park partials, waves 0-3 add + finish
    if (w >= 4) {
#pragma unroll
        for (int qi = 0; qi < 4; qi++) {
#pragma unroll
            for (int mt = 0; mt < 4; mt++)
                *(f32x4*)(&psum[wq][qi * 16 + lm][mt * 16 + g * 4]) = o[qi][mt];
            if (g == 0)
                psum[wq][qi * 16 + lm][64] = ol[qi][0];
        }
    }
    __syncthreads();
    if (w < 4) {
        const int b = bh >> 4, h = bh & 15;
        bf16* ostw = ost[wq];
#pragma unroll
        for (int qi = 0; qi < 4; qi++) {
            float tot = ol[qi][0] + psum[wq][qi * 16 + lm][64];
            float inv = 1.0f / tot;
#pragma unroll
            for (int mt = 0; mt < 4; mt++) {
                f32x4 ps = *(const f32x4*)(&psum[wq][qi * 16 + lm][mt * 16 + g * 4]);
                bf16x4 ov;
#pragma unroll
                for (int r = 0; r < 4; r++)
                    ov[r] = (bf16)((o[qi][mt][r] + ps[r]) * inv);
                *(bf16x4*)(ostw + (qi * 16 + lm) * 72 + mt * 16 + g * 4) = ov;
            }
        }
        __builtin_amdgcn_s_waitcnt(0);  // lgkmcnt(0) before re-reading own region
#pragma unroll
        for (int it = 0; it < 8; it++) {
            int cc = it * 64 + lane;
            int q  = cc >> 3, ch = cc & 7;
            bf16x8 t = *(const bf16x8*)(ostw + q * 72 + ch * 8);
            *(bf16x8*)(attn + (size_t)(b * 2048 + q0 + q) * 1024 + h * 64 + ch * 8) = t;
        }
    }
}

// ---------------------------------------------------------------------------
extern "C" void kernel_launch(void* const* d_in, const int* in_sizes, int n_in,
                              void* d_out, int out_size, void* d_ws, size_t ws_size,
                              hipStream_t stream) {
    const float* query = (const float*)d_in[0];
    const float* key   = (const float*)d_in[1];
    const float* value = (const float*)d_in[2];
    const float* Wq    = (const float*)d_in[3];
    const float* bq    = (const float*)d_in[4];
    const float* Wk    = (const float*)d_in[5];
    const float* Wv    = (const float*)d_in[6];
    const float* Wo    = (const float*)d_in[7];
    const float* bo    = (const float*)d_in[8];

    char* ws = (char*)d_ws;
    bf16* Xq  = (bf16*)(ws);
    bf16* Xk  = (bf16*)(ws + ((size_t)8  << 20));
    bf16* Xv  = (bf16*)(ws + ((size_t)16 << 20));
    bf16* Wqb = (bf16*)(ws + ((size_t)24 << 20));
    bf16* Wkb = (bf16*)(ws + ((size_t)26 << 20));
    bf16* Wvb = (bf16*)(ws + ((size_t)28 << 20));
    bf16* Wob = (bf16*)(ws + ((size_t)30 << 20));
    bf16* Qs  = (bf16*)(ws + ((size_t)32 << 20));
    bf16* Ksw = (bf16*)(ws + ((size_t)40 << 20));
    bf16* Vsw = (bf16*)(ws + ((size_t)48 << 20));
    bf16* attn = Xq;  // Xq dead after projections

    cvt_bf16_kernel<<<dim3(16384, 1, 1), 256, 0, stream>>>(
        query, key, value, Wq, Wk, Wv, Wo, Xq, Xk, Xv, Wqb, Wkb, Wvb, Wob);

    gemm4_kernel<128><<<dim3(8, 32, 3), 256, 0, stream>>>(
        Xq, Xk, Xv, attn, Wqb, Wkb, Wvb, Wob, bq, bo, Qs, Ksw, Vsw, (float*)d_out, 0);

    attn_kernel<<<dim3(256, 1, 1), 512, 0, stream>>>(Qs, Ksw, Vsw, attn);

    // R9: output projection now uses the 128x128 tile shape (was BN=64):
    // 1.5x less staging traffic per FLOP, half the barrier-drains.
    gemm4_kernel<128><<<dim3(8, 32, 1), 256, 0, stream>>>(
        Xq, Xk, Xv, attn, Wqb, Wkb, Wvb, Wob, bq, bo, Qs, Ksw, Vsw, (float*)d_out, 3);
}

// Round 11
// 197.796 us; speedup vs baseline: 1.0288x; 1.0288x over previous
//
#include <hip/hip_runtime.h>

typedef __bf16 bf16;
typedef __bf16 bf16x8 __attribute__((ext_vector_type(8)));
typedef __bf16 bf16x4 __attribute__((ext_vector_type(4)));
typedef float  f32x4  __attribute__((ext_vector_type(4)));

#define MFMA_BF16(a, b, c) __builtin_amdgcn_mfma_f32_16x16x32_bf16((a), (b), (c), 0, 0, 0)

// Problem constants: B=2, L=2048, E=1024, H=16, D=64; M=B*L=4096, K=N=E=1024.

__device__ __forceinline__ void async_load16(const bf16* g, const bf16* l) {
    auto gp = (const __attribute__((address_space(1))) unsigned int*)(unsigned long long)(const void*)g;
    auto lp = (__attribute__((address_space(3))) unsigned int*)(unsigned int)(unsigned long long)(const void*)l;
    __builtin_amdgcn_global_load_lds(gp, lp, 16, 0, 0);
}

// ---------------------------------------------------------------------------
// fp32 -> bf16 conversion. Flat 1D grid (16384 blocks), 4 elems/thread.
// Layout: 3 activations of 2^22 elems, then 4 weights of 2^20 elems.
__global__ void cvt_bf16_kernel(
    const float* __restrict__ s0, const float* __restrict__ s1, const float* __restrict__ s2,
    const float* __restrict__ s3, const float* __restrict__ s4, const float* __restrict__ s5,
    const float* __restrict__ s6,
    bf16* __restrict__ d0, bf16* __restrict__ d1, bf16* __restrict__ d2,
    bf16* __restrict__ d3, bf16* __restrict__ d4, bf16* __restrict__ d5,
    bf16* __restrict__ d6)
{
    unsigned e = (blockIdx.x * 256 + threadIdx.x) * 4;
    const float* src; bf16* dst; unsigned off;
    if (e < 12582912u) {
        unsigned which = e >> 22;
        src = which == 0 ? s0 : (which == 1 ? s1 : s2);
        dst = which == 0 ? d0 : (which == 1 ? d1 : d2);
        off = e & 4194303u;
    } else {
        unsigned ew = e - 12582912u;
        unsigned which = ew >> 20;
        src = which == 0 ? s3 : (which == 1 ? s4 : (which == 2 ? s5 : s6));
        dst = which == 0 ? d3 : (which == 1 ? d4 : (which == 2 ? d5 : d6));
        off = ew & 1048575u;
    }
    float4 f = *(const float4*)(src + off);
    bf16x4 o;
    o.x = (bf16)f.x; o.y = (bf16)f.y; o.z = (bf16)f.z; o.w = (bf16)f.w;
    *(bf16x4*)(dst + off) = o;
}

// ---------------------------------------------------------------------------
// Tiled bf16 GEMM, BM=128 x BN (template), BK=32 x 2 stripes/barrier,
// 4 waves (2x2).
//
// XCD-aware tile remap (T1): HW assigns xcd = blockid % 8, and blockid =
// blockIdx.x + 8*blockIdx.y, so without remap each XCD got ONE feature-tile
// x ALL token-tiles -> zero B-panel reuse inside an XCD L2 (measured 101 MB
// FETCH vs ~30 MB ideal). Remap: c = flat&7 (the XCD), j = flat>>3;
// feature_tile = j&7, token_tile = c*(gy/8) + (j>>3). Per-XCD working set =
// weights 2 MB + token-panels 1 MB < 4 MB L2.  [R3: gemm4<128> left top-5]
//
// Two BK=32 stripes staged per barrier pair: halves lockstep drains (32->16).
//
// R10: launch_bounds min-waves raised 2 -> 3 for BN=128 (z=0-2 grid is 768
// blocks = exactly 3/CU; LDS 32 KB x 3 = 96 KB fits, VGPR_Count 64 << cap).
// The 3rd resident block's MFMA covers the other blocks' staging drains --
// the same cross-block-overlap mechanism that made BN=64@2-blocks beat
// BN=128@1-block for the output projection (R9/R10: +6.9 us regression,
// reverted).
//
// Orientation per output so the 4 r-values (C/D rows) are address-consecutive
// in the destination -> all stores bf16x4/float4:
//  z=0 (A=Wq, B=Xq): +bq, *0.125*log2e -> Qs [B,H,L,D]
//  z=1 (A=Wk, B=Xk): -> Ksw fragment-major (d lands on j)
//  z=2 (A=Xv, B=Wv): -> Vsw fragment-major (token lands on j)
//  z=3 (A=Wo, B=attn): +bo -> out fp32 (feature-contiguous float4)
template<int BN>
__global__ __launch_bounds__(256, (BN == 128) ? 3 : 4) void gemm4_kernel(
    const bf16* __restrict__ Xq, const bf16* __restrict__ Xk, const bf16* __restrict__ Xv,
    const bf16* __restrict__ Ao,
    const bf16* __restrict__ Wq, const bf16* __restrict__ Wk, const bf16* __restrict__ Wv,
    const bf16* __restrict__ Wo,
    const float* __restrict__ bq, const float* __restrict__ bo,
    bf16* __restrict__ Qs, bf16* __restrict__ Ksw, bf16* __restrict__ Vsw,
    float* __restrict__ out, int zbase)
{
    const int z = zbase + blockIdx.z;
    const bf16 *Amat, *Bmat;
    if (z == 0)      { Amat = Wq; Bmat = Xq; }
    else if (z == 1) { Amat = Wk; Bmat = Xk; }
    else if (z == 2) { Amat = Xv; Bmat = Wv; }
    else             { Amat = Wo; Bmat = Ao; }

    // XCD-aware remap (bijective: gy is a multiple of 8 for both launches)
    const int flat = blockIdx.x + 8 * blockIdx.y;
    const int c    = flat & 7;           // XCD (blockid % 8)
    const int j    = flat >> 3;          // position within this XCD's chunk
    const int ft   = j & 7;              // feature tile (8 x 128)
    const int tt   = c * (gridDim.y >> 3) + (j >> 3);  // token tile

    const int m0 = (z == 2 ? tt : ft) * 128;
    const int n0 = (z == 2 ? ft : tt) * BN;

    __shared__ __align__(16) bf16 lA[2][128 * 32];
    __shared__ __align__(16) bf16 lB[2][BN * 32];

    const int tid  = threadIdx.x;
    const int w    = tid >> 6;
    const int lane = tid & 63;
    const int lm   = lane & 15;
    const int g    = lane >> 4;
    const int wm   = (w & 1) * 64;
    const int wn   = (w >> 1) * (BN / 2);
    constexpr int NT = BN / 32;
    constexpr int T  = (128 + BN) / 64;

    f32x4 acc[4][NT] = {};

    for (int kb2 = 0; kb2 < 16; kb2++) {
        __syncthreads();
#pragma unroll
        for (int st = 0; st < 2; st++) {
            int kb = kb2 * 2 + st;
#pragma unroll
            for (int t = 0; t < T; t++) {
                int s   = (t * 4 + w) * 64 + lane;
                int row = s >> 2;
                int gs  = s & 3;
                int gg  = gs ^ ((row >> 1) & 3);
                if (row < 128)
                    async_load16(Amat + (size_t)(m0 + row) * 1024 + kb * 32 + gg * 8,
                                 lA[st] + s * 8);
                else
                    async_load16(Bmat + (size_t)(n0 + row - 128) * 1024 + kb * 32 + gg * 8,
                                 lB[st] + (s - 512) * 8);
            }
        }
        __syncthreads();

#pragma unroll
        for (int st = 0; st < 2; st++) {
            bf16x8 af[4], bfr[NT];
#pragma unroll
            for (int mt = 0; mt < 4; mt++) {
                int row = wm + mt * 16 + lm;
                af[mt] = *(const bf16x8*)(lA[st] + row * 32 + ((g ^ ((row >> 1) & 3)) << 3));
            }
#pragma unroll
            for (int nt = 0; nt < NT; nt++) {
                int row = wn + nt * 16 + lm;
                bfr[nt] = *(const bf16x8*)(lB[st] + row * 32 + ((g ^ ((row >> 1) & 3)) << 3));
            }
#pragma unroll
            for (int mt = 0; mt < 4; mt++)
#pragma unroll
                for (int nt = 0; nt < NT; nt++)
                    acc[mt][nt] = MFMA_BF16(af[mt], bfr[nt], acc[mt][nt]);
        }
    }

    if (z == 3) {
#pragma unroll
        for (int mt = 0; mt < 4; mt++) {
            int mb = m0 + wm + mt * 16 + g * 4;
            f32x4 bov = *(const f32x4*)(bo + mb);
#pragma unroll
            for (int nt = 0; nt < NT; nt++) {
                int n = n0 + wn + nt * 16 + lm;
                f32x4 val;
#pragma unroll
                for (int r = 0; r < 4; r++) val[r] = acc[mt][nt][r] + bov[r];
                *(f32x4*)(out + (size_t)n * 1024 + mb) = val;
            }
        }
    } else if (z == 2) {
#pragma unroll
        for (int mt = 0; mt < 4; mt++) {
            int mb   = m0 + wm + mt * 16 + g * 4;
            int b    = mb >> 11;
            int lpos = mb & 2047;
            int kb2  = lpos >> 6, kc = (lpos >> 5) & 1, gv = (lpos >> 3) & 3, j0 = lpos & 7;
#pragma unroll
            for (int nt = 0; nt < NT; nt++) {
                int n = n0 + wn + nt * 16 + lm;
                int h = n >> 6, mt2 = (n >> 4) & 3, lmv = n & 15;
                bf16x4 ov;
#pragma unroll
                for (int r = 0; r < 4; r++) ov[r] = (bf16)acc[mt][nt][r];
                *(bf16x4*)(Vsw + (size_t)(b * 16 + h) * 131072 +
                           (size_t)((kb2 * 8 + mt2 * 2 + kc) * 64 + gv * 16 + lmv) * 8 + j0) = ov;
            }
        }
    } else if (z == 1) {
#pragma unroll
        for (int mt = 0; mt < 4; mt++) {
            int mb = m0 + wm + mt * 16 + g * 4;
            int h  = mb >> 6;
            int f  = (mb >> 5) & 1, gk = (mb >> 3) & 3, j0 = mb & 7;
#pragma unroll
            for (int nt = 0; nt < NT; nt++) {
                int n    = n0 + wn + nt * 16 + lm;
                int b    = n >> 11;
                int lpos = n & 2047;
                int kb2  = lpos >> 6;
                int rem  = lpos & 63;
                int cc   = ((rem >> 4) & 2) | ((rem >> 2) & 1);
                int lmk  = ((rem >> 1) & 12) | (rem & 3);
                bf16x4 ov;
#pragma unroll
                for (int r = 0; r < 4; r++) ov[r] = (bf16)acc[mt][nt][r];
                *(bf16x4*)(Ksw + (size_t)(b * 16 + h) * 131072 +
                           (size_t)((kb2 * 8 + cc * 2 + f) * 64 + gk * 16 + lmk) * 8 + j0) = ov;
            }
        }
    } else {
        const float qscale = 0.18033688011112042f;  // 1/8 * log2(e)
#pragma unroll
        for (int mt = 0; mt < 4; mt++) {
            int mb  = m0 + wm + mt * 16 + g * 4;
            int h   = mb >> 6;
            int dd0 = mb & 63;
            f32x4 bqv = *(const f32x4*)(bq + mb);
#pragma unroll
            for (int nt = 0; nt < NT; nt++) {
                int n    = n0 + wn + nt * 16 + lm;
                int b    = n >> 11;
                int lpos = n & 2047;
                bf16x4 ov;
#pragma unroll
                for (int r = 0; r < 4; r++)
                    ov[r] = (bf16)((acc[mt][nt][r] + bqv[r]) * qscale);
                *(bf16x4*)(Qs + (size_t)((b * 16 + h) * 2048 + lpos) * 64 + dd0) = ov;
            }
        }
    }
}

// ---------------------------------------------------------------------------
// Flash attention v10 (BEST: 196.6 us total): K-split, 8 waves,
// register-direct, MFMA denominator. R9's s_sleep stagger regressed +1.7 us
// (phase offset does not persist across iterations -- pair re-locks at the
// first memory stall), reverted.
// Structure: 256 blocks x 8 waves (2/SIMD); wave w: q-chunk (w&3)*64,
// k-half (w>>2)*1024 tokens. The no-max softmax (p = exp2(s)) makes
// disjoint-k partial (O, lsum) exactly additive -> one LDS combine pass.
// Denominator rides the matrix pipe: ones-row MFMA column-sums P (replaces
// ~64 VALU adds/iter + end shuffles; every lane ends with the full sum).
__global__ __launch_bounds__(512, 2) void attn_kernel(
    const bf16* __restrict__ Qs, const bf16* __restrict__ Ksw,
    const bf16* __restrict__ Vsw, bf16* __restrict__ attn)
{
    const int tid  = threadIdx.x;
    const int w    = tid >> 6;        // 0..7
    const int wq   = w & 3;           // q sub-chunk
    const int wk   = w >> 2;          // k half
    const int lane = tid & 63;
    const int lm   = lane & 15;
    const int g    = lane >> 4;
    const int i    = blockIdx.x;      // 256 blocks
    const int bh   = ((i & 7) << 2) | ((i >> 3) & 3);  // 4 heads per XCD
    const int q0   = (i >> 5) * 256 + wq * 64;         // 64 q-rows per wave

    const bf16* Qh = Qs  + (size_t)bh * 131072;
    const bf16* Kh = Ksw + (size_t)bh * 131072 + (size_t)wk * 65536;  // k-half base
    const bf16* Vh = Vsw + (size_t)bh * 131072 + (size_t)wk * 65536;

    // psum: 4 x 64 x 68 f32 (cols 0..63 = partial O, col 64 = partial lsum)
    // ost: 4 waves x 64 x 72 bf16. Total ~104 KB -> 1 block/CU.
    __shared__ __align__(16) float psum[4][64][68];
    __shared__ __align__(16) bf16 ost[4][64 * 72];

    // Q fragments (B operand): lane lm = q-row, k(=d) = f*32 + g*8 + j
    bf16x8 qf[4][2];
#pragma unroll
    for (int qi = 0; qi < 4; qi++)
#pragma unroll
        for (int f = 0; f < 2; f++)
            qf[qi][f] = *(const bf16x8*)(Qh + (size_t)(q0 + qi * 16 + lm) * 64 + f * 32 + g * 8);

    const f32x4 fzero = {0.0f, 0.0f, 0.0f, 0.0f};
    f32x4 o[4][4] = {};
    f32x4 ol[4] = {};                 // denominator accumulators (ones-row MFMA)
    const bf16x8 ones = {(bf16)1.0f, (bf16)1.0f, (bf16)1.0f, (bf16)1.0f,
                         (bf16)1.0f, (bf16)1.0f, (bf16)1.0f, (bf16)1.0f};

    // prologue: stripe-0 (of this k-half) fragments into registers
    bf16x8 kf[8], vf[8];
#pragma unroll
    for (int t = 0; t < 8; t++)
        kf[t] = *(const bf16x8*)(Kh + ((size_t)t * 64 + lane) * 8);
#pragma unroll
    for (int t = 0; t < 8; t++)
        vf[t] = *(const bf16x8*)(Vh + ((size_t)t * 64 + lane) * 8);

    for (int kb = 0; kb < 16; kb++) {
        // next-stripe base (clamped: last iteration re-reads stripe 15, unused)
        const int kn = (kb < 15) ? kb + 1 : 15;
        const bf16* Kn = Kh + (size_t)kn * 4096;
        const bf16* Vn = Vh + (size_t)kn * 4096;

        // QK^T + softmax per fragment (4 independent chains -> ILP):
        // s[c][r] = S at k = 32*(c>>1) + 8g + 4*(c&1) + r, q = lm
        bf16x8 pb[4][2];
        __builtin_amdgcn_s_setprio(1);
#pragma unroll
        for (int qi = 0; qi < 4; qi++) {
            f32x4 s[4];
#pragma unroll
            for (int c = 0; c < 4; c++) {
                s[c] = MFMA_BF16(kf[2 * c],     qf[qi][0], fzero);
                s[c] = MFMA_BF16(kf[2 * c + 1], qf[qi][1], s[c]);
            }
            // flat p[]: index kc*8 + j, j 0..3 <- s[2kc][j], j 4..7 <- s[2kc+1][j-4]
            float p[16];
#pragma unroll
            for (int c = 0; c < 4; c++)
#pragma unroll
                for (int r = 0; r < 4; r++)
                    p[(c >> 1) * 8 + (c & 1) * 4 + r] = __builtin_amdgcn_exp2f(s[c][r]);
#pragma unroll
            for (int kc = 0; kc < 2; kc++)
#pragma unroll
                for (int jj = 0; jj < 8; jj++)     // adjacent writes -> cvt_pk
                    pb[qi][kc][jj] = (bf16)p[kc * 8 + jj];
        }
        __builtin_amdgcn_s_setprio(0);

        // reload kf with next stripe -- latency hides under PV (40 MFMAs)
#pragma unroll
        for (int t = 0; t < 8; t++)
            kf[t] = *(const bf16x8*)(Kn + ((size_t)t * 64 + lane) * 8);

        // O^T += V^T P (shared vf fragment feeds all 4 q-fragments);
        // denominator rides the matrix pipe: ones-row MFMA sums P columns.
        __builtin_amdgcn_s_setprio(1);
#pragma unroll
        for (int kc = 0; kc < 2; kc++) {
#pragma unroll
            for (int mt = 0; mt < 4; mt++) {
                bf16x8 vfv = vf[mt * 2 + kc];
#pragma unroll
                for (int qi = 0; qi < 4; qi++)
                    o[qi][mt] = MFMA_BF16(vfv, pb[qi][kc], o[qi][mt]);
            }
#pragma unroll
            for (int qi = 0; qi < 4; qi++)
                ol[qi] = MFMA_BF16(ones, pb[qi][kc], ol[qi]);
        }
        __builtin_amdgcn_s_setprio(0);

        // reload vf with next stripe -- hides under next QK^T + softmax
#pragma unroll
        for (int t = 0; t < 8; t++)
            vf[t] = *(const bf16x8*)(Vn + ((size_t)t * 64 + lane) * 8);
    }

    // ol[qi][r] now holds sum_k P[q=qi*16+lm, k] over this k-half,
    // replicated across r and across g -- no shuffles needed.

    // k-split combine: waves 4-7 park partials, waves 0-3 add + finish
    if (w >= 4) {
#pragma unroll
        for (int qi = 0; qi < 4; qi++) {
#pragma unroll
            for (int mt = 0; mt < 4; mt++)
                *(f32x4*)(&psum[wq][qi * 16 + lm][mt * 16 + g * 4]) = o[qi][mt];
            if (g == 0)
                psum[wq][qi * 16 + lm][64] = ol[qi][0];
        }
    }
    __syncthreads();
    if (w < 4) {
        const int b = bh >> 4, h = bh & 15;
        bf16* ostw = ost[wq];
#pragma unroll
        for (int qi = 0; qi < 4; qi++) {
            float tot = ol[qi][0] + psum[wq][qi * 16 + lm][64];
            float inv = 1.0f / tot;
#pragma unroll
            for (int mt = 0; mt < 4; mt++) {
                f32x4 ps = *(const f32x4*)(&psum[wq][qi * 16 + lm][mt * 16 + g * 4]);
                bf16x4 ov;
#pragma unroll
                for (int r = 0; r < 4; r++)
                    ov[r] = (bf16)((o[qi][mt][r] + ps[r]) * inv);
                *(bf16x4*)(ostw + (qi * 16 + lm) * 72 + mt * 16 + g * 4) = ov;
            }
        }
        __builtin_amdgcn_s_waitcnt(0);  // lgkmcnt(0) before re-reading own region
#pragma unroll
        for (int it = 0; it < 8; it++) {
            int cc = it * 64 + lane;
            int q  = cc >> 3, ch = cc & 7;
            bf16x8 t = *(const bf16x8*)(ostw + q * 72 + ch * 8);
            *(bf16x8*)(attn + (size_t)(b * 2048 + q0 + q) * 1024 + h * 64 + ch * 8) = t;
        }
    }
}

// ---------------------------------------------------------------------------
extern "C" void kernel_launch(void* const* d_in, const int* in_sizes, int n_in,
                              void* d_out, int out_size, void* d_ws, size_t ws_size,
                              hipStream_t stream) {
    const float* query = (const float*)d_in[0];
    const float* key   = (const float*)d_in[1];
    const float* value = (const float*)d_in[2];
    const float* Wq    = (const float*)d_in[3];
    const float* bq    = (const float*)d_in[4];
    const float* Wk    = (const float*)d_in[5];
    const float* Wv    = (const float*)d_in[6];
    const float* Wo    = (const float*)d_in[7];
    const float* bo    = (const float*)d_in[8];

    char* ws = (char*)d_ws;
    bf16* Xq  = (bf16*)(ws);
    bf16* Xk  = (bf16*)(ws + ((size_t)8  << 20));
    bf16* Xv  = (bf16*)(ws + ((size_t)16 << 20));
    bf16* Wqb = (bf16*)(ws + ((size_t)24 << 20));
    bf16* Wkb = (bf16*)(ws + ((size_t)26 << 20));
    bf16* Wvb = (bf16*)(ws + ((size_t)28 << 20));
    bf16* Wob = (bf16*)(ws + ((size_t)30 << 20));
    bf16* Qs  = (bf16*)(ws + ((size_t)32 << 20));
    bf16* Ksw = (bf16*)(ws + ((size_t)40 << 20));
    bf16* Vsw = (bf16*)(ws + ((size_t)48 << 20));
    bf16* attn = Xq;  // Xq dead after projections

    cvt_bf16_kernel<<<dim3(16384, 1, 1), 256, 0, stream>>>(
        query, key, value, Wq, Wk, Wv, Wo, Xq, Xk, Xv, Wqb, Wkb, Wvb, Wob);

    gemm4_kernel<128><<<dim3(8, 32, 3), 256, 0, stream>>>(
        Xq, Xk, Xv, attn, Wqb, Wkb, Wvb, Wob, bq, bo, Qs, Ksw, Vsw, (float*)d_out, 0);

    attn_kernel<<<dim3(256, 1, 1), 512, 0, stream>>>(Qs, Ksw, Vsw, attn);

    // R10: output projection back to BN=64 / 512 blocks (2 blocks/CU) --
    // the BN=128/256-block variant was 1 block/CU and regressed +6.9 us.
    gemm4_kernel<64><<<dim3(8, 64, 1), 256, 0, stream>>>(
        Xq, Xk, Xv, attn, Wqb, Wkb, Wvb, Wob, bq, bo, Qs, Ksw, Vsw, (float*)d_out, 3);
}

// Round 12
// 196.958 us; speedup vs baseline: 1.0332x; 1.0043x over previous
//
#include <hip/hip_runtime.h>

typedef __bf16 bf16;
typedef __bf16 bf16x8 __attribute__((ext_vector_type(8)));
typedef __bf16 bf16x4 __attribute__((ext_vector_type(4)));
typedef float  f32x4  __attribute__((ext_vector_type(4)));

#define MFMA_BF16(a, b, c) __builtin_amdgcn_mfma_f32_16x16x32_bf16((a), (b), (c), 0, 0, 0)

// Problem constants: B=2, L=2048, E=1024, H=16, D=64; M=B*L=4096, K=N=E=1024.

__device__ __forceinline__ void async_load16(const bf16* g, const bf16* l) {
    auto gp = (const __attribute__((address_space(1))) unsigned int*)(unsigned long long)(const void*)g;
    auto lp = (__attribute__((address_space(3))) unsigned int*)(unsigned int)(unsigned long long)(const void*)l;
    __builtin_amdgcn_global_load_lds(gp, lp, 16, 0, 0);
}

// ---------------------------------------------------------------------------
// fp32 -> bf16 conversion. Flat 1D grid (16384 blocks), 4 elems/thread.
// Layout: 3 activations of 2^22 elems, then 4 weights of 2^20 elems.
__global__ void cvt_bf16_kernel(
    const float* __restrict__ s0, const float* __restrict__ s1, const float* __restrict__ s2,
    const float* __restrict__ s3, const float* __restrict__ s4, const float* __restrict__ s5,
    const float* __restrict__ s6,
    bf16* __restrict__ d0, bf16* __restrict__ d1, bf16* __restrict__ d2,
    bf16* __restrict__ d3, bf16* __restrict__ d4, bf16* __restrict__ d5,
    bf16* __restrict__ d6)
{
    unsigned e = (blockIdx.x * 256 + threadIdx.x) * 4;
    const float* src; bf16* dst; unsigned off;
    if (e < 12582912u) {
        unsigned which = e >> 22;
        src = which == 0 ? s0 : (which == 1 ? s1 : s2);
        dst = which == 0 ? d0 : (which == 1 ? d1 : d2);
        off = e & 4194303u;
    } else {
        unsigned ew = e - 12582912u;
        unsigned which = ew >> 20;
        src = which == 0 ? s3 : (which == 1 ? s4 : (which == 2 ? s5 : s6));
        dst = which == 0 ? d3 : (which == 1 ? d4 : (which == 2 ? d5 : d6));
        off = ew & 1048575u;
    }
    float4 f = *(const float4*)(src + off);
    bf16x4 o;
    o.x = (bf16)f.x; o.y = (bf16)f.y; o.z = (bf16)f.z; o.w = (bf16)f.w;
    *(bf16x4*)(dst + off) = o;
}

// ---------------------------------------------------------------------------
// Tiled bf16 GEMM, BM=128 x BN (template), BK=32 x 2 stripes/barrier,
// 4 waves (2x2).
//
// XCD-aware tile remap (T1): HW assigns xcd = blockid % 8, and blockid =
// blockIdx.x + 8*blockIdx.y, so without remap each XCD got ONE feature-tile
// x ALL token-tiles -> zero B-panel reuse inside an XCD L2 (measured 101 MB
// FETCH vs ~30 MB ideal). Remap: c = flat&7 (the XCD), j = flat>>3;
// feature_tile = j&7, token_tile = c*(gy/8) + (j>>3). Per-XCD working set =
// weights 2 MB + token-panels 1 MB < 4 MB L2.  [R3: gemm4<128> left top-5]
//
// Two BK=32 stripes staged per barrier pair: halves lockstep drains (32->16).
//
// R11: launch_bounds back to 2 for BN=128 -- R10's raise to 3 was neutral
// (occupancy was never bounds-limited: VGPR=64, LDS 32 KB already admit the
// grid's 3 blocks/CU; the bound only constrains regalloc).
//
// Orientation per output so the 4 r-values (C/D rows) are address-consecutive
// in the destination -> all stores bf16x4/float4:
//  z=0 (A=Wq, B=Xq): +bq, *0.125*log2e -> Qs [B,H,L,D]
//  z=1 (A=Wk, B=Xk): -> Ksw fragment-major (d lands on j)
//  z=2 (A=Xv, B=Wv): -> Vsw fragment-major (token lands on j)
//  z=3 (A=Wo, B=attn): +bo -> out fp32 (feature-contiguous float4)
template<int BN>
__global__ __launch_bounds__(256, (BN == 128) ? 2 : 4) void gemm4_kernel(
    const bf16* __restrict__ Xq, const bf16* __restrict__ Xk, const bf16* __restrict__ Xv,
    const bf16* __restrict__ Ao,
    const bf16* __restrict__ Wq, const bf16* __restrict__ Wk, const bf16* __restrict__ Wv,
    const bf16* __restrict__ Wo,
    const float* __restrict__ bq, const float* __restrict__ bo,
    bf16* __restrict__ Qs, bf16* __restrict__ Ksw, bf16* __restrict__ Vsw,
    float* __restrict__ out, int zbase)
{
    const int z = zbase + blockIdx.z;
    const bf16 *Amat, *Bmat;
    if (z == 0)      { Amat = Wq; Bmat = Xq; }
    else if (z == 1) { Amat = Wk; Bmat = Xk; }
    else if (z == 2) { Amat = Xv; Bmat = Wv; }
    else             { Amat = Wo; Bmat = Ao; }

    // XCD-aware remap (bijective: gy is a multiple of 8 for both launches)
    const int flat = blockIdx.x + 8 * blockIdx.y;
    const int c    = flat & 7;           // XCD (blockid % 8)
    const int j    = flat >> 3;          // position within this XCD's chunk
    const int ft   = j & 7;              // feature tile (8 x 128)
    const int tt   = c * (gridDim.y >> 3) + (j >> 3);  // token tile

    const int m0 = (z == 2 ? tt : ft) * 128;
    const int n0 = (z == 2 ? ft : tt) * BN;

    __shared__ __align__(16) bf16 lA[2][128 * 32];
    __shared__ __align__(16) bf16 lB[2][BN * 32];

    const int tid  = threadIdx.x;
    const int w    = tid >> 6;
    const int lane = tid & 63;
    const int lm   = lane & 15;
    const int g    = lane >> 4;
    const int wm   = (w & 1) * 64;
    const int wn   = (w >> 1) * (BN / 2);
    constexpr int NT = BN / 32;
    constexpr int T  = (128 + BN) / 64;

    f32x4 acc[4][NT] = {};

    for (int kb2 = 0; kb2 < 16; kb2++) {
        __syncthreads();
#pragma unroll
        for (int st = 0; st < 2; st++) {
            int kb = kb2 * 2 + st;
#pragma unroll
            for (int t = 0; t < T; t++) {
                int s   = (t * 4 + w) * 64 + lane;
                int row = s >> 2;
                int gs  = s & 3;
                int gg  = gs ^ ((row >> 1) & 3);
                if (row < 128)
                    async_load16(Amat + (size_t)(m0 + row) * 1024 + kb * 32 + gg * 8,
                                 lA[st] + s * 8);
                else
                    async_load16(Bmat + (size_t)(n0 + row - 128) * 1024 + kb * 32 + gg * 8,
                                 lB[st] + (s - 512) * 8);
            }
        }
        __syncthreads();

#pragma unroll
        for (int st = 0; st < 2; st++) {
            bf16x8 af[4], bfr[NT];
#pragma unroll
            for (int mt = 0; mt < 4; mt++) {
                int row = wm + mt * 16 + lm;
                af[mt] = *(const bf16x8*)(lA[st] + row * 32 + ((g ^ ((row >> 1) & 3)) << 3));
            }
#pragma unroll
            for (int nt = 0; nt < NT; nt++) {
                int row = wn + nt * 16 + lm;
                bfr[nt] = *(const bf16x8*)(lB[st] + row * 32 + ((g ^ ((row >> 1) & 3)) << 3));
            }
#pragma unroll
            for (int mt = 0; mt < 4; mt++)
#pragma unroll
                for (int nt = 0; nt < NT; nt++)
                    acc[mt][nt] = MFMA_BF16(af[mt], bfr[nt], acc[mt][nt]);
        }
    }

    if (z == 3) {
#pragma unroll
        for (int mt = 0; mt < 4; mt++) {
            int mb = m0 + wm + mt * 16 + g * 4;
            f32x4 bov = *(const f32x4*)(bo + mb);
#pragma unroll
            for (int nt = 0; nt < NT; nt++) {
                int n = n0 + wn + nt * 16 + lm;
                f32x4 val;
#pragma unroll
                for (int r = 0; r < 4; r++) val[r] = acc[mt][nt][r] + bov[r];
                *(f32x4*)(out + (size_t)n * 1024 + mb) = val;
            }
        }
    } else if (z == 2) {
#pragma unroll
        for (int mt = 0; mt < 4; mt++) {
            int mb   = m0 + wm + mt * 16 + g * 4;
            int b    = mb >> 11;
            int lpos = mb & 2047;
            int kb2  = lpos >> 6, kc = (lpos >> 5) & 1, gv = (lpos >> 3) & 3, j0 = lpos & 7;
#pragma unroll
            for (int nt = 0; nt < NT; nt++) {
                int n = n0 + wn + nt * 16 + lm;
                int h = n >> 6, mt2 = (n >> 4) & 3, lmv = n & 15;
                bf16x4 ov;
#pragma unroll
                for (int r = 0; r < 4; r++) ov[r] = (bf16)acc[mt][nt][r];
                *(bf16x4*)(Vsw + (size_t)(b * 16 + h) * 131072 +
                           (size_t)((kb2 * 8 + mt2 * 2 + kc) * 64 + gv * 16 + lmv) * 8 + j0) = ov;
            }
        }
    } else if (z == 1) {
#pragma unroll
        for (int mt = 0; mt < 4; mt++) {
            int mb = m0 + wm + mt * 16 + g * 4;
            int h  = mb >> 6;
            int f  = (mb >> 5) & 1, gk = (mb >> 3) & 3, j0 = mb & 7;
#pragma unroll
            for (int nt = 0; nt < NT; nt++) {
                int n    = n0 + wn + nt * 16 + lm;
                int b    = n >> 11;
                int lpos = n & 2047;
                int kb2  = lpos >> 6;
                int rem  = lpos & 63;
                int cc   = ((rem >> 4) & 2) | ((rem >> 2) & 1);
                int lmk  = ((rem >> 1) & 12) | (rem & 3);
                bf16x4 ov;
#pragma unroll
                for (int r = 0; r < 4; r++) ov[r] = (bf16)acc[mt][nt][r];
                *(bf16x4*)(Ksw + (size_t)(b * 16 + h) * 131072 +
                           (size_t)((kb2 * 8 + cc * 2 + f) * 64 + gk * 16 + lmk) * 8 + j0) = ov;
            }
        }
    } else {
        const float qscale = 0.18033688011112042f;  // 1/8 * log2(e)
#pragma unroll
        for (int mt = 0; mt < 4; mt++) {
            int mb  = m0 + wm + mt * 16 + g * 4;
            int h   = mb >> 6;
            int dd0 = mb & 63;
            f32x4 bqv = *(const f32x4*)(bq + mb);
#pragma unroll
            for (int nt = 0; nt < NT; nt++) {
                int n    = n0 + wn + nt * 16 + lm;
                int b    = n >> 11;
                int lpos = n & 2047;
                bf16x4 ov;
#pragma unroll
                for (int r = 0; r < 4; r++)
                    ov[r] = (bf16)((acc[mt][nt][r] + bqv[r]) * qscale);
                *(bf16x4*)(Qs + (size_t)((b * 16 + h) * 2048 + lpos) * 64 + dd0) = ov;
            }
        }
    }
}

// ---------------------------------------------------------------------------
// Flash attention v12 = v10 (K-split, 8 waves, register-direct, MFMA
// denominator; 196.6 us total anchor) MINUS the s_setprio fences.
// Rationale: setprio was added in the v5 regime (1 independent wave/SIMD,
// m191-style +7). v10 runs 2 IDENTICAL in-phase waves/SIMD -- both raise
// priority simultaneously (zero arbitration benefit), while the
// side-effecting intrinsics act as scheduling fences that pin the QK/SM/PV
// phase boundaries and stop the compiler interleaving the 4 independent qi
// chains and prefetch loads across them. m190 measured setprio as a net
// NEGATIVE on the lockstep-GEMM structure, which this kernel now resembles
// (MFMA-bound, symmetric waves).
// Structure: 256 blocks x 8 waves (2/SIMD); wave w: q-chunk (w&3)*64,
// k-half (w>>2)*1024 tokens. No-max softmax (p = exp2(s)) -> disjoint-k
// partials exactly additive -> one LDS combine pass. Denominator rides the
// matrix pipe (ones-row MFMA column-sums P; no end shuffles).
__global__ __launch_bounds__(512, 2) void attn_kernel(
    const bf16* __restrict__ Qs, const bf16* __restrict__ Ksw,
    const bf16* __restrict__ Vsw, bf16* __restrict__ attn)
{
    const int tid  = threadIdx.x;
    const int w    = tid >> 6;        // 0..7
    const int wq   = w & 3;           // q sub-chunk
    const int wk   = w >> 2;          // k half
    const int lane = tid & 63;
    const int lm   = lane & 15;
    const int g    = lane >> 4;
    const int i    = blockIdx.x;      // 256 blocks
    const int bh   = ((i & 7) << 2) | ((i >> 3) & 3);  // 4 heads per XCD
    const int q0   = (i >> 5) * 256 + wq * 64;         // 64 q-rows per wave

    const bf16* Qh = Qs  + (size_t)bh * 131072;
    const bf16* Kh = Ksw + (size_t)bh * 131072 + (size_t)wk * 65536;  // k-half base
    const bf16* Vh = Vsw + (size_t)bh * 131072 + (size_t)wk * 65536;

    // psum: 4 x 64 x 68 f32 (cols 0..63 = partial O, col 64 = partial lsum)
    // ost: 4 waves x 64 x 72 bf16. Total ~104 KB -> 1 block/CU.
    __shared__ __align__(16) float psum[4][64][68];
    __shared__ __align__(16) bf16 ost[4][64 * 72];

    // Q fragments (B operand): lane lm = q-row, k(=d) = f*32 + g*8 + j
    bf16x8 qf[4][2];
#pragma unroll
    for (int qi = 0; qi < 4; qi++)
#pragma unroll
        for (int f = 0; f < 2; f++)
            qf[qi][f] = *(const bf16x8*)(Qh + (size_t)(q0 + qi * 16 + lm) * 64 + f * 32 + g * 8);

    const f32x4 fzero = {0.0f, 0.0f, 0.0f, 0.0f};
    f32x4 o[4][4] = {};
    f32x4 ol[4] = {};                 // denominator accumulators (ones-row MFMA)
    const bf16x8 ones = {(bf16)1.0f, (bf16)1.0f, (bf16)1.0f, (bf16)1.0f,
                         (bf16)1.0f, (bf16)1.0f, (bf16)1.0f, (bf16)1.0f};

    // prologue: stripe-0 (of this k-half) fragments into registers
    bf16x8 kf[8], vf[8];
#pragma unroll
    for (int t = 0; t < 8; t++)
        kf[t] = *(const bf16x8*)(Kh + ((size_t)t * 64 + lane) * 8);
#pragma unroll
    for (int t = 0; t < 8; t++)
        vf[t] = *(const bf16x8*)(Vh + ((size_t)t * 64 + lane) * 8);

    for (int kb = 0; kb < 16; kb++) {
        // next-stripe base (clamped: last iteration re-reads stripe 15, unused)
        const int kn = (kb < 15) ? kb + 1 : 15;
        const bf16* Kn = Kh + (size_t)kn * 4096;
        const bf16* Vn = Vh + (size_t)kn * 4096;

        // QK^T + softmax per fragment (4 independent chains -> ILP):
        // s[c][r] = S at k = 32*(c>>1) + 8g + 4*(c&1) + r, q = lm
        bf16x8 pb[4][2];
#pragma unroll
        for (int qi = 0; qi < 4; qi++) {
            f32x4 s[4];
#pragma unroll
            for (int c = 0; c < 4; c++) {
                s[c] = MFMA_BF16(kf[2 * c],     qf[qi][0], fzero);
                s[c] = MFMA_BF16(kf[2 * c + 1], qf[qi][1], s[c]);
            }
            // flat p[]: index kc*8 + j, j 0..3 <- s[2kc][j], j 4..7 <- s[2kc+1][j-4]
            float p[16];
#pragma unroll
            for (int c = 0; c < 4; c++)
#pragma unroll
                for (int r = 0; r < 4; r++)
                    p[(c >> 1) * 8 + (c & 1) * 4 + r] = __builtin_amdgcn_exp2f(s[c][r]);
#pragma unroll
            for (int kc = 0; kc < 2; kc++)
#pragma unroll
                for (int jj = 0; jj < 8; jj++)     // adjacent writes -> cvt_pk
                    pb[qi][kc][jj] = (bf16)p[kc * 8 + jj];
        }

        // reload kf with next stripe -- latency hides under PV (40 MFMAs)
#pragma unroll
        for (int t = 0; t < 8; t++)
            kf[t] = *(const bf16x8*)(Kn + ((size_t)t * 64 + lane) * 8);

        // O^T += V^T P (shared vf fragment feeds all 4 q-fragments);
        // denominator rides the matrix pipe: ones-row MFMA sums P columns.
#pragma unroll
        for (int kc = 0; kc < 2; kc++) {
#pragma unroll
            for (int mt = 0; mt < 4; mt++) {
                bf16x8 vfv = vf[mt * 2 + kc];
#pragma unroll
                for (int qi = 0; qi < 4; qi++)
                    o[qi][mt] = MFMA_BF16(vfv, pb[qi][kc], o[qi][mt]);
            }
#pragma unroll
            for (int qi = 0; qi < 4; qi++)
                ol[qi] = MFMA_BF16(ones, pb[qi][kc], ol[qi]);
        }

        // reload vf with next stripe -- hides under next QK^T + softmax
#pragma unroll
        for (int t = 0; t < 8; t++)
            vf[t] = *(const bf16x8*)(Vn + ((size_t)t * 64 + lane) * 8);
    }

    // ol[qi][r] now holds sum_k P[q=qi*16+lm, k] over this k-half,
    // replicated across r and across g -- no shuffles needed.

    // k-split combine: waves 4-7 park partials, waves 0-3 add + finish
    if (w >= 4) {
#pragma unroll
        for (int qi = 0; qi < 4; qi++) {
#pragma unroll
            for (int mt = 0; mt < 4; mt++)
                *(f32x4*)(&psum[wq][qi * 16 + lm][mt * 16 + g * 4]) = o[qi][mt];
            if (g == 0)
                psum[wq][qi * 16 + lm][64] = ol[qi][0];
        }
    }
    __syncthreads();
    if (w < 4) {
        const int b = bh >> 4, h = bh & 15;
        bf16* ostw = ost[wq];
#pragma unroll
        for (int qi = 0; qi < 4; qi++) {
            float tot = ol[qi][0] + psum[wq][qi * 16 + lm][64];
            float inv = 1.0f / tot;
#pragma unroll
            for (int mt = 0; mt < 4; mt++) {
                f32x4 ps = *(const f32x4*)(&psum[wq][qi * 16 + lm][mt * 16 + g * 4]);
                bf16x4 ov;
#pragma unroll
                for (int r = 0; r < 4; r++)
                    ov[r] = (bf16)((o[qi][mt][r] + ps[r]) * inv);
                *(bf16x4*)(ostw + (qi * 16 + lm) * 72 + mt * 16 + g * 4) = ov;
            }
        }
        __builtin_amdgcn_s_waitcnt(0);  // lgkmcnt(0) before re-reading own region
#pragma unroll
        for (int it = 0; it < 8; it++) {
            int cc = it * 64 + lane;
            int q  = cc >> 3, ch = cc & 7;
            bf16x8 t = *(const bf16x8*)(ostw + q * 72 + ch * 8);
            *(bf16x8*)(attn + (size_t)(b * 2048 + q0 + q) * 1024 + h * 64 + ch * 8) = t;
        }
    }
}

// ---------------------------------------------------------------------------
extern "C" void kernel_launch(void* const* d_in, const int* in_sizes, int n_in,
                              void* d_out, int out_size, void* d_ws, size_t ws_size,
                              hipStream_t stream) {
    const float* query = (const float*)d_in[0];
    const float* key   = (const float*)d_in[1];
    const float* value = (const float*)d_in[2];
    const float* Wq    = (const float*)d_in[3];
    const float* bq    = (const float*)d_in[4];
    const float* Wk    = (const float*)d_in[5];
    const float* Wv    = (const float*)d_in[6];
    const float* Wo    = (const float*)d_in[7];
    const float* bo    = (const float*)d_in[8];

    char* ws = (char*)d_ws;
    bf16* Xq  = (bf16*)(ws);
    bf16* Xk  = (bf16*)(ws + ((size_t)8  << 20));
    bf16* Xv  = (bf16*)(ws + ((size_t)16 << 20));
    bf16* Wqb = (bf16*)(ws + ((size_t)24 << 20));
    bf16* Wkb = (bf16*)(ws + ((size_t)26 << 20));
    bf16* Wvb = (bf16*)(ws + ((size_t)28 << 20));
    bf16* Wob = (bf16*)(ws + ((size_t)30 << 20));
    bf16* Qs  = (bf16*)(ws + ((size_t)32 << 20));
    bf16* Ksw = (bf16*)(ws + ((size_t)40 << 20));
    bf16* Vsw = (bf16*)(ws + ((size_t)48 << 20));
    bf16* attn = Xq;  // Xq dead after projections

    cvt_bf16_kernel<<<dim3(16384, 1, 1), 256, 0, stream>>>(
        query, key, value, Wq, Wk, Wv, Wo, Xq, Xk, Xv, Wqb, Wkb, Wvb, Wob);

    gemm4_kernel<128><<<dim3(8, 32, 3), 256, 0, stream>>>(
        Xq, Xk, Xv, attn, Wqb, Wkb, Wvb, Wob, bq, bo, Qs, Ksw, Vsw, (float*)d_out, 0);

    attn_kernel<<<dim3(256, 1, 1), 512, 0, stream>>>(Qs, Ksw, Vsw, attn);

    // Output projection: BN=64 / 512 blocks (2 blocks/CU) -- the
    // BN=128/256-block variant was 1 block/CU and regressed +6.9 us (R10).
    gemm4_kernel<64><<<dim3(8, 64, 1), 256, 0, stream>>>(
        Xq, Xk, Xv, attn, Wqb, Wkb, Wvb, Wob, bq, bo, Qs, Ksw, Vsw, (float*)d_out, 3);
}